// Round 16
// baseline (1127.972 us; speedup 1.0000x reference)
//
#include <hip/hip_runtime.h>
#include <hip/hip_bf16.h>
#include <stdint.h>

#define T_SEQ 32
#define BATCH 128
#define EMB   512
#define HID   1024
#define VOC   32000
#define G3    (3 * HID)            // 3072
#define MROWS (T_SEQ * BATCH)      // 4096
#define BHID  (BATCH * HID)
#define NTILE 8000                 // 32 row-bands x 250 col-tiles (128x128)

typedef __bf16 bf16_t;
typedef __bf16 bf16x8 __attribute__((ext_vector_type(8)));
typedef __bf16 bf16x4 __attribute__((ext_vector_type(4)));
typedef float  f32x4  __attribute__((ext_vector_type(4)));

#define MFMA(a, b, c) __builtin_amdgcn_mfma_f32_16x16x32_bf16((a), (b), (c), 0, 0, 0)

union U64cast  { bf16x4 v; unsigned long long u; };
union U128cast { f32x4 v; unsigned long long u[2]; };

__device__ __forceinline__ unsigned flag_ld(const unsigned* p) {
    return __hip_atomic_load(p, __ATOMIC_RELAXED, __HIP_MEMORY_SCOPE_SYSTEM);
}
__device__ __forceinline__ void flag_st(unsigned* p, unsigned v) {
    __hip_atomic_store(p, v, __ATOMIC_RELAXED, __HIP_MEMORY_SCOPE_SYSTEM);
}

// ---------------------------------------------------------------------------
// Fused f32 -> bf16 conversion: all 7 tensors in ONE launch (R15, verified).
// ---------------------------------------------------------------------------
__global__ void fused_cvt_kernel(
    const float* __restrict__ w_ih0, const float* __restrict__ w_hh0,
    const float* __restrict__ w_ih1, const float* __restrict__ w_hh1,
    const float* __restrict__ w_dec, const float* __restrict__ enc_hid,
    bf16_t* __restrict__ Wih0b, bf16_t* __restrict__ Whh0b,
    bf16_t* __restrict__ Wih1b, bf16_t* __restrict__ Whh1b,
    bf16_t* __restrict__ Wdecb, bf16_t* __restrict__ h0ib,
    bf16_t* __restrict__ h1ib) {
    const int b = blockIdx.x;
    const float* src;
    bf16_t* dst;
    int base;
    if (b < 1536)       { src = w_ih0;          dst = Wih0b; base = b; }
    else if (b < 4608)  { src = w_hh0;          dst = Whh0b; base = b - 1536; }
    else if (b < 7680)  { src = w_ih1;          dst = Wih1b; base = b - 4608; }
    else if (b < 10752) { src = w_hh1;          dst = Whh1b; base = b - 7680; }
    else if (b < 42752) { src = w_dec;          dst = Wdecb; base = b - 10752; }
    else if (b < 42880) { src = enc_hid;        dst = h0ib;  base = b - 42752; }
    else                { src = enc_hid + BHID; dst = h1ib;  base = b - 42880; }
    const int i = base * 1024 + threadIdx.x * 4;
    float4 v = *(const float4*)(src + i);
    dst[i + 0] = (bf16_t)v.x;
    dst[i + 1] = (bf16_t)v.y;
    dst[i + 2] = (bf16_t)v.z;
    dst[i + 3] = (bf16_t)v.w;
}

// ---------------------------------------------------------------------------
// Embedding gather
// ---------------------------------------------------------------------------
__global__ void embed_kernel(const int* __restrict__ x,
                             const float* __restrict__ emb,
                             bf16_t* __restrict__ X) {
    int m = blockIdx.x;            // 0..4095
    int t = m >> 7, b = m & 127;
    int tok = (t == 0) ? 1 : x[b * T_SEQ + t];
    const float* src = emb + (size_t)tok * EMB;
    bf16_t* dst = X + (size_t)m * EMB;
    int c = threadIdx.x * 4;
    float4 v = *(const float4*)(src + c);
    dst[c + 0] = (bf16_t)v.x;
    dst[c + 1] = (bf16_t)v.y;
    dst[c + 2] = (bf16_t)v.z;
    dst[c + 3] = (bf16_t)v.w;
}

// ---------------------------------------------------------------------------
#define GLOAD_LDS16(g, l)                                                    \
    __builtin_amdgcn_global_load_lds(                                        \
        (const __attribute__((address_space(1))) void*)(g),                  \
        (__attribute__((address_space(3))) void*)(l), 16, 0, 0)

// ---------------------------------------------------------------------------
// GEMM 128x128 (m97 structure) — Gi0 GEMM (frozen).
// ---------------------------------------------------------------------------
template <int BIAS>
__global__ __launch_bounds__(256) void gemm_bf16_kernel(
    const bf16_t* __restrict__ A, const bf16_t* __restrict__ B,
    const float* __restrict__ bias, float* __restrict__ C,
    int M, int N, int K) {
    __shared__ __align__(16) bf16_t As[128 * 32];
    __shared__ __align__(16) bf16_t Bs[128 * 32];

    const int nbm = gridDim.y, nbn = gridDim.x;
    const int nwg = nbm * nbn;
    int lin = blockIdx.y * nbn + blockIdx.x;
    if ((nwg & 7) == 0) {
        int xcd = lin & 7, idx = lin >> 3;
        lin = xcd * (nwg >> 3) + idx;
    }
    const int bm = (lin % nbm) * 128;
    const int bn = (lin / nbm) * 128;

    const int tid  = threadIdx.x;
    const int lane = tid & 63;
    const int w    = tid >> 6;
    const int wr   = w >> 1, wc = w & 1;

    f32x4 acc[4][4] = {};

    const int lrow = tid >> 2;
    const int lcol = (tid & 3) * 8;
    const bf16_t* ag = A + (size_t)(bm + lrow) * K + lcol;
    const bf16_t* bg = B + (size_t)(bn + lrow) * K + lcol;
    bf16_t* asl0 = As + lrow * 32 + lcol;
    bf16_t* asl1 = As + (lrow + 64) * 32 + lcol;
    bf16_t* bsl0 = Bs + lrow * 32 + lcol;
    bf16_t* bsl1 = Bs + (lrow + 64) * 32 + lcol;

    const int r16 = lane & 15;
    const int kh  = (lane >> 4) * 8;

    for (int k0 = 0; k0 < K; k0 += 32) {
        GLOAD_LDS16(ag + k0, asl0);
        GLOAD_LDS16(ag + (size_t)64 * K + k0, asl1);
        GLOAD_LDS16(bg + k0, bsl0);
        GLOAD_LDS16(bg + (size_t)64 * K + k0, bsl1);
        __syncthreads();

        bf16x8 af[4], bf[4];
#pragma unroll
        for (int mi = 0; mi < 4; ++mi)
            af[mi] = *(const bf16x8*)(As + (wr * 64 + mi * 16 + r16) * 32 + kh);
#pragma unroll
        for (int ni = 0; ni < 4; ++ni)
            bf[ni] = *(const bf16x8*)(Bs + (wc * 64 + ni * 16 + r16) * 32 + kh);
#pragma unroll
        for (int mi = 0; mi < 4; ++mi)
#pragma unroll
            for (int ni = 0; ni < 4; ++ni)
                acc[mi][ni] = MFMA(af[mi], bf[ni], acc[mi][ni]);
        __syncthreads();
    }

#pragma unroll
    for (int mi = 0; mi < 4; ++mi) {
        const int row0 = bm + wr * 64 + mi * 16 + (lane >> 4) * 4;
#pragma unroll
        for (int ni = 0; ni < 4; ++ni) {
            const int col = bn + wc * 64 + ni * 16 + r16;
            float bv = 0.f;
            if (BIAS) bv = bias[col];
#pragma unroll
            for (int r = 0; r < 4; ++r)
                C[(size_t)(row0 + r) * N + col] = acc[mi][ni][r] + bv;
        }
    }
}

// ---------------------------------------------------------------------------
// SCAN + STEAL kernel: 448 blocks x 256 threads, 48 KB static LDS
// (3 blocks/CU capacity -> ALL blocks co-resident for any dispatch order;
// one-way dep DAG -> deadlock-free).
//  bid   0- 63: L0 scan   (R15 per-wave flags; Sg in bf16)
//  bid  64-127: G  stage  (gi1 -> Gi slot t, sc f32)
//  bid 128-191: L1 scan
//  bid 192-447: logits GEMM steal-workers from t=0 (gated on L1 wave-flags)
// Scan blocks join the steal loop after their scan. GEMM = 4-wave 128x128
// m97 body, nt C-stores. Scan compute runs at setprio(1) so co-located GEMM
// waves don't starve the critical path.
// ---------------------------------------------------------------------------
__global__ __launch_bounds__(256, 1) void scan_steal_kernel(
    const bf16_t* __restrict__ h0ib, const bf16_t* __restrict__ h1ib,
    const float* __restrict__ enc_hid,
    const bf16_t* __restrict__ whh0, const bf16_t* __restrict__ wih1,
    const bf16_t* __restrict__ whh1,
    const float* __restrict__ bhh0, const float* __restrict__ bih1,
    const float* __restrict__ bhh1,
    float* __restrict__ Gi, bf16_t* __restrict__ H0b,
    bf16_t* __restrict__ H1b,
    const bf16_t* __restrict__ Wdecb, const float* __restrict__ bdec,
    float* __restrict__ out, unsigned* __restrict__ wfl) {
    __shared__ __align__(16) bf16_t SgB[4][3][128][16];   // 48 KB
    __shared__ unsigned tileShared;

    const int tid  = threadIdx.x;
    const int lane = tid & 63;
    const int bid  = blockIdx.x;
    const int FL0 = 0, FG = 256, FL1 = 512;

    if (bid < 192) {
        // =====================  SCAN ROLES (R15 + bf16 Sg)  ================
        const int w    = tid >> 6;
        const int role = bid >> 6;
        const int cb   = bid & 63;
        const int c0   = cb * 16;
        const int r16  = lane & 15;
        const int kq   = (lane >> 4) * 8;

        const bf16_t* whh = role == 0 ? whh0 : (role == 1 ? wih1 : whh1);
        const float*  bia = role == 0 ? bhh0 : (role == 1 ? bih1 : bhh1);

        bf16x8 wf[3][8];
#pragma unroll
        for (int g = 0; g < 3; ++g)
#pragma unroll
            for (int kf = 0; kf < 8; ++kf)
                wf[g][kf] = *(const bf16x8*)(
                    whh + (size_t)(g * HID + c0 + r16) * HID + w * 256 +
                    kf * 32 + kq);

        const int cg   = tid & 3;
        const int rloc = tid >> 2;
        const int ce   = c0 + cg * 4;

        float bh[3][4];
#pragma unroll
        for (int g = 0; g < 3; ++g)
#pragma unroll
            for (int j = 0; j < 4; ++j) bh[g][j] = bia[g * HID + ce + j];

        float hp[2][4];
        if (role != 1) {
            const float* h0f = enc_hid + (role == 2 ? BHID : 0);
#pragma unroll
            for (int i = 0; i < 2; ++i)
#pragma unroll
                for (int j = 0; j < 4; ++j)
                    hp[i][j] = h0f[(size_t)(rloc + i * 64) * HID + ce + j];
        }

        f32x4 gi[2][3];
        if (role == 0) {
#pragma unroll
            for (int i = 0; i < 2; ++i) {
                const size_t gb = (size_t)(rloc + i * 64) * G3 + ce;
                gi[i][0] = *(const f32x4*)(Gi + gb);
                gi[i][1] = *(const f32x4*)(Gi + gb + HID);
                gi[i][2] = *(const f32x4*)(Gi + gb + 2 * HID);
            }
        }

        for (int t = 0; t < T_SEQ; ++t) {
            // ---- wait on producers (per-wave flag granularity) ----
            if (role == 0) {
                if (t && tid < 64) {
#pragma unroll
                    for (int j = 0; j < 4; ++j)
                        while (flag_ld(&wfl[FL0 + tid * 4 + j]) < (unsigned)t)
                            __builtin_amdgcn_s_sleep(1);
                }
            } else if (role == 1) {
                if (tid < 64) {
#pragma unroll
                    for (int j = 0; j < 4; ++j)
                        while (flag_ld(&wfl[FL0 + tid * 4 + j]) <
                               (unsigned)(t + 1))
                            __builtin_amdgcn_s_sleep(1);
                }
            } else {
                if (tid < 64) {
                    if (t) {
#pragma unroll
                        for (int j = 0; j < 4; ++j)
                            while (flag_ld(&wfl[FL1 + tid * 4 + j]) <
                                   (unsigned)t)
                                __builtin_amdgcn_s_sleep(1);
                    }
                } else if (tid < 68) {
                    while (flag_ld(&wfl[FG + cb * 4 + (tid - 64)]) <
                           (unsigned)(t + 1))
                        __builtin_amdgcn_s_sleep(1);
                }
            }
            __syncthreads();
            __builtin_amdgcn_s_setprio(1);

            // ---- role 2: gi1 sc-read ----
            if (role == 2) {
#pragma unroll
                for (int i = 0; i < 2; ++i) {
                    const size_t gb =
                        ((size_t)t * BATCH + rloc + i * 64) * G3 + ce;
#pragma unroll
                    for (int g = 0; g < 3; ++g) {
                        U128cast u;
                        const unsigned long long* p =
                            (const unsigned long long*)(Gi + gb + g * HID);
                        u.u[0] = __hip_atomic_load(p, __ATOMIC_RELAXED,
                                                   __HIP_MEMORY_SCOPE_SYSTEM);
                        u.u[1] = __hip_atomic_load(p + 1, __ATOMIC_RELAXED,
                                                   __HIP_MEMORY_SCOPE_SYSTEM);
                        gi[i][g] = u.v;
                    }
                }
            }

            const bf16_t* hb =
                role == 0 ? (t ? H0b + (size_t)(t - 1) * BHID : h0ib)
              : role == 1 ? (H0b + (size_t)t * BHID)
                          : (t ? H1b + (size_t)(t - 1) * BHID : h1ib);

            f32x4 acc[3][8] = {};
            bf16x8 af[4][8];
#define LD_GROUP(buf, kf)                                                    \
    {                                                                        \
        const int kbase = w * 256 + (kf) * 32 + kq;                          \
        _Pragma("unroll") for (int rf = 0; rf < 8; ++rf)                     \
            af[buf][rf] =                                                    \
                *(const bf16x8*)(hb + (size_t)(rf * 16 + r16) * HID + kbase); \
    }
            LD_GROUP(0, 0)
            LD_GROUP(1, 1)
            LD_GROUP(2, 2)
#pragma unroll
            for (int kf = 0; kf < 8; ++kf) {
                if (kf + 3 < 8) LD_GROUP((kf + 3) & 3, kf + 3)
#pragma unroll
                for (int rf = 0; rf < 8; ++rf) {
                    acc[0][rf] = MFMA(af[kf & 3][rf], wf[0][kf], acc[0][rf]);
                    acc[1][rf] = MFMA(af[kf & 3][rf], wf[1][kf], acc[1][rf]);
                    acc[2][rf] = MFMA(af[kf & 3][rf], wf[2][kf], acc[2][rf]);
                }
            }
#undef LD_GROUP

#pragma unroll
            for (int g = 0; g < 3; ++g)
#pragma unroll
                for (int rf = 0; rf < 8; ++rf)
#pragma unroll
                    for (int r = 0; r < 4; ++r)
                        SgB[w][g][rf * 16 + (lane >> 4) * 4 + r][r16] =
                            (bf16_t)acc[g][rf][r];
            __syncthreads();

            // ---- epilogue ----
#pragma unroll
            for (int i = 0; i < 2; ++i) {
                const int row = rloc + i * 64;
                float gr[4] = {0, 0, 0, 0}, gz[4] = {0, 0, 0, 0},
                      gn[4] = {0, 0, 0, 0};
#pragma unroll
                for (int ks = 0; ks < 4; ++ks) {
                    bf16x4 vr = *(const bf16x4*)&SgB[ks][0][row][cg * 4];
                    bf16x4 vz = *(const bf16x4*)&SgB[ks][1][row][cg * 4];
                    bf16x4 vn = *(const bf16x4*)&SgB[ks][2][row][cg * 4];
#pragma unroll
                    for (int j = 0; j < 4; ++j) {
                        gr[j] += (float)vr[j];
                        gz[j] += (float)vz[j];
                        gn[j] += (float)vn[j];
                    }
                }
                if (role == 1) {
                    const size_t gb = ((size_t)t * BATCH + row) * G3 + ce;
                    U128cast s0, s1, s2;
#pragma unroll
                    for (int j = 0; j < 4; ++j) {
                        s0.v[j] = gr[j] + bh[0][j];
                        s1.v[j] = gz[j] + bh[1][j];
                        s2.v[j] = gn[j] + bh[2][j];
                    }
                    unsigned long long* p0 = (unsigned long long*)(Gi + gb);
                    unsigned long long* p1 = (unsigned long long*)(Gi + gb + HID);
                    unsigned long long* p2 = (unsigned long long*)(Gi + gb + 2 * HID);
                    __hip_atomic_store(p0, s0.u[0], __ATOMIC_RELAXED, __HIP_MEMORY_SCOPE_SYSTEM);
                    __hip_atomic_store(p0 + 1, s0.u[1], __ATOMIC_RELAXED, __HIP_MEMORY_SCOPE_SYSTEM);
                    __hip_atomic_store(p1, s1.u[0], __ATOMIC_RELAXED, __HIP_MEMORY_SCOPE_SYSTEM);
                    __hip_atomic_store(p1 + 1, s1.u[1], __ATOMIC_RELAXED, __HIP_MEMORY_SCOPE_SYSTEM);
                    __hip_atomic_store(p2, s2.u[0], __ATOMIC_RELAXED, __HIP_MEMORY_SCOPE_SYSTEM);
                    __hip_atomic_store(p2 + 1, s2.u[1], __ATOMIC_RELAXED, __HIP_MEMORY_SCOPE_SYSTEM);
                } else {
                    U64cast hb4;
#pragma unroll
                    for (int j = 0; j < 4; ++j) {
                        float rr = 1.f / (1.f + __expf(-(gi[i][0][j] + gr[j] + bh[0][j])));
                        float zz = 1.f / (1.f + __expf(-(gi[i][1][j] + gz[j] + bh[1][j])));
                        float nn = tanhf(gi[i][2][j] + rr * (gn[j] + bh[2][j]));
                        float h  = (1.f - zz) * nn + zz * hp[i][j];
                        hp[i][j] = h;
                        hb4.v[j] = (bf16_t)h;
                    }
                    bf16_t* dst = (role == 0 ? H0b : H1b) +
                                  (size_t)t * BHID + (size_t)row * HID + ce;
                    __hip_atomic_store((unsigned long long*)dst, hb4.u,
                                       __ATOMIC_RELAXED,
                                       __HIP_MEMORY_SCOPE_SYSTEM);
                }
            }

            // ---- per-wave early publish ----
            asm volatile("s_waitcnt vmcnt(0)" ::: "memory");
            __builtin_amdgcn_sched_barrier(0);
            if (lane == 0)
                flag_st(&wfl[role * 256 + cb * 4 + w], (unsigned)(t + 1));
            __builtin_amdgcn_s_setprio(0);

            if (role == 0 && t + 1 < T_SEQ) {
#pragma unroll
                for (int i = 0; i < 2; ++i) {
                    const size_t gb =
                        ((size_t)(t + 1) * BATCH + rloc + i * 64) * G3 + ce;
                    gi[i][0] = *(const f32x4*)(Gi + gb);
                    gi[i][1] = *(const f32x4*)(Gi + gb + HID);
                    gi[i][2] = *(const f32x4*)(Gi + gb + 2 * HID);
                }
            }
            __syncthreads();   // Sg protection for next iteration
        }
    }

    // =====================  WORK-STEAL LOGITS GEMM  ========================
    {
        bf16_t* As = (bf16_t*)SgB;           // 8 KB
        bf16_t* Bs = As + 128 * 32;          // 8 KB
        unsigned* ctr = wfl + 768;
        const int w4 = tid >> 6, wr = w4 >> 1, wc = w4 & 1;
        const int lrow = tid >> 2, lcol = (tid & 3) * 8;
        const int r16 = lane & 15, kh = (lane >> 4) * 8;

        int have = 0;
        for (;;) {
            __syncthreads();
            if (tid == 0)
                tileShared = __hip_atomic_fetch_add(ctr, 1u, __ATOMIC_RELAXED,
                                                    __HIP_MEMORY_SCOPE_AGENT);
            __syncthreads();
            const int tile = (int)tileShared;
            if (tile >= NTILE) break;

            const int rt = tile / 250, ct = tile - rt * 250;
            const int bm = rt * 128, bn = ct * 128;
            if (rt + 1 > have) {
                if (tid < 64) {
#pragma unroll
                    for (int j = 0; j < 4; ++j)
                        while (flag_ld(&wfl[512 + tid * 4 + j]) <
                               (unsigned)(rt + 1))
                            __builtin_amdgcn_s_sleep(16);
                }
                __syncthreads();
                have = rt + 1;
            }

            const bf16_t* ag = H1b + (size_t)(bm + lrow) * HID + lcol;
            const bf16_t* bg = Wdecb + (size_t)(bn + lrow) * HID + lcol;
            f32x4 acc[4][4] = {};

            for (int k0 = 0; k0 < HID; k0 += 32) {
                GLOAD_LDS16(ag + k0, As + lrow * 32 + lcol);
                GLOAD_LDS16(ag + (size_t)64 * HID + k0,
                            As + (lrow + 64) * 32 + lcol);
                GLOAD_LDS16(bg + k0, Bs + lrow * 32 + lcol);
                GLOAD_LDS16(bg + (size_t)64 * HID + k0,
                            Bs + (lrow + 64) * 32 + lcol);
                __syncthreads();

                bf16x8 af[4], bf[4];
#pragma unroll
                for (int mi = 0; mi < 4; ++mi)
                    af[mi] = *(const bf16x8*)(As + (wr * 64 + mi * 16 + r16) * 32 + kh);
#pragma unroll
                for (int ni = 0; ni < 4; ++ni)
                    bf[ni] = *(const bf16x8*)(Bs + (wc * 64 + ni * 16 + r16) * 32 + kh);
#pragma unroll
                for (int mi = 0; mi < 4; ++mi)
#pragma unroll
                    for (int ni = 0; ni < 4; ++ni)
                        acc[mi][ni] = MFMA(af[mi], bf[ni], acc[mi][ni]);
                __syncthreads();
            }

#pragma unroll
            for (int mi = 0; mi < 4; ++mi) {
                const int row0 = bm + wr * 64 + mi * 16 + (lane >> 4) * 4;
#pragma unroll
                for (int ni = 0; ni < 4; ++ni) {
                    const int col = bn + wc * 64 + ni * 16 + r16;
                    const float bv = bdec[col];
#pragma unroll
                    for (int r = 0; r < 4; ++r)
                        __builtin_nontemporal_store(
                            acc[mi][ni][r] + bv,
                            &out[(size_t)(row0 + r) * VOC + col]);
                }
            }
        }
    }
}

// ---------------------------------------------------------------------------
extern "C" void kernel_launch(void* const* d_in, const int* in_sizes, int n_in,
                              void* d_out, int out_size, void* d_ws, size_t ws_size,
                              hipStream_t stream) {
    const int*   x        = (const int*)d_in[0];
    const float* enc_hid  = (const float*)d_in[2];   // [2,128,1024]
    const float* emb      = (const float*)d_in[3];
    const float* w_ih0    = (const float*)d_in[4];
    const float* w_hh0    = (const float*)d_in[5];
    const float* b_ih0    = (const float*)d_in[6];
    const float* b_hh0    = (const float*)d_in[7];
    const float* w_ih1    = (const float*)d_in[8];
    const float* w_hh1    = (const float*)d_in[9];
    const float* b_ih1    = (const float*)d_in[10];
    const float* b_hh1    = (const float*)d_in[11];
    const float* w_dec    = (const float*)d_in[12];
    const float* b_dec    = (const float*)d_in[13];
    float* out = (float*)d_out;

    char* ws = (char*)d_ws;
    size_t off = 0;
    auto alloc = [&](size_t bytes) {
        void* p = ws + off;
        off += (bytes + 255) & ~(size_t)255;
        return p;
    };
    unsigned* wfl  = (unsigned*)alloc(4096);   // 768 wave-flags + ctr @768
    bf16_t* Xb     = (bf16_t*)alloc((size_t)MROWS * EMB * 2);
    bf16_t* Wih0b  = (bf16_t*)alloc((size_t)G3 * EMB * 2);
    bf16_t* Whh0b  = (bf16_t*)alloc((size_t)G3 * HID * 2);
    bf16_t* Wih1b  = (bf16_t*)alloc((size_t)G3 * HID * 2);
    bf16_t* Whh1b  = (bf16_t*)alloc((size_t)G3 * HID * 2);
    bf16_t* Wdecb  = (bf16_t*)alloc((size_t)VOC * HID * 2);
    bf16_t* h0ib   = (bf16_t*)alloc((size_t)BATCH * HID * 2);
    bf16_t* h1ib   = (bf16_t*)alloc((size_t)BATCH * HID * 2);
    float*  Gi     = (float*)alloc((size_t)MROWS * G3 * 4);
    bf16_t* H0b    = (bf16_t*)alloc((size_t)MROWS * HID * 2);
    bf16_t* H1b    = (bf16_t*)alloc((size_t)MROWS * HID * 2);

    hipMemsetAsync(wfl, 0, 4096, stream);

    fused_cvt_kernel<<<43008, 256, 0, stream>>>(
        w_ih0, w_hh0, w_ih1, w_hh1, w_dec, enc_hid,
        Wih0b, Whh0b, Wih1b, Whh1b, Wdecb, h0ib, h1ib);

    embed_kernel<<<MROWS, 128, 0, stream>>>(x, emb, Xb);

    // Gi0 = X @ w_ih0^T + b_ih0  -> [4096, 3072]
    gemm_bf16_kernel<1><<<dim3(G3 / 128, MROWS / 128), 256, 0, stream>>>(
        Xb, Wih0b, b_ih0, Gi, MROWS, G3, EMB);

    // scan (L0 + G + L1) with logits GEMM overlapped via work-steal
    scan_steal_kernel<<<448, 256, 0, stream>>>(
        h0ib, h1ib, enc_hid, Whh0b, Wih1b, Whh1b,
        b_hh0, b_ih1, b_hh1, Gi, H0b, H1b,
        Wdecb, b_dec, out, wfl);
}

// Round 17
// 929.861 us; speedup vs baseline: 1.2131x; 1.2131x over previous
//
#include <hip/hip_runtime.h>
#include <hip/hip_bf16.h>
#include <stdint.h>

#define T_SEQ 32
#define BATCH 128
#define EMB   512
#define HID   1024
#define VOC   32000
#define G3    (3 * HID)            // 3072
#define MROWS (T_SEQ * BATCH)      // 4096
#define BHID  (BATCH * HID)

typedef __bf16 bf16_t;
typedef __bf16 bf16x8 __attribute__((ext_vector_type(8)));
typedef __bf16 bf16x4 __attribute__((ext_vector_type(4)));
typedef float  f32x4  __attribute__((ext_vector_type(4)));

#define MFMA(a, b, c) __builtin_amdgcn_mfma_f32_16x16x32_bf16((a), (b), (c), 0, 0, 0)

union U64cast  { bf16x4 v; unsigned long long u; };
union U128cast { f32x4 v; unsigned long long u[2]; };

__device__ __forceinline__ unsigned flag_ld(const unsigned* p) {
    return __hip_atomic_load(p, __ATOMIC_RELAXED, __HIP_MEMORY_SCOPE_SYSTEM);
}
__device__ __forceinline__ void flag_st(unsigned* p, unsigned v) {
    __hip_atomic_store(p, v, __ATOMIC_RELAXED, __HIP_MEMORY_SCOPE_SYSTEM);
}

// ---------------------------------------------------------------------------
// Fused f32 -> bf16 conversion: all 7 tensors in ONE launch (R15, verified).
// ---------------------------------------------------------------------------
__global__ void fused_cvt_kernel(
    const float* __restrict__ w_ih0, const float* __restrict__ w_hh0,
    const float* __restrict__ w_ih1, const float* __restrict__ w_hh1,
    const float* __restrict__ w_dec, const float* __restrict__ enc_hid,
    bf16_t* __restrict__ Wih0b, bf16_t* __restrict__ Whh0b,
    bf16_t* __restrict__ Wih1b, bf16_t* __restrict__ Whh1b,
    bf16_t* __restrict__ Wdecb, bf16_t* __restrict__ h0ib,
    bf16_t* __restrict__ h1ib) {
    const int b = blockIdx.x;
    const float* src;
    bf16_t* dst;
    int base;
    if (b < 1536)       { src = w_ih0;          dst = Wih0b; base = b; }
    else if (b < 4608)  { src = w_hh0;          dst = Whh0b; base = b - 1536; }
    else if (b < 7680)  { src = w_ih1;          dst = Wih1b; base = b - 4608; }
    else if (b < 10752) { src = w_hh1;          dst = Whh1b; base = b - 7680; }
    else if (b < 42752) { src = w_dec;          dst = Wdecb; base = b - 10752; }
    else if (b < 42880) { src = enc_hid;        dst = h0ib;  base = b - 42752; }
    else                { src = enc_hid + BHID; dst = h1ib;  base = b - 42880; }
    const int i = base * 1024 + threadIdx.x * 4;
    float4 v = *(const float4*)(src + i);
    dst[i + 0] = (bf16_t)v.x;
    dst[i + 1] = (bf16_t)v.y;
    dst[i + 2] = (bf16_t)v.z;
    dst[i + 3] = (bf16_t)v.w;
}

// ---------------------------------------------------------------------------
// Embedding gather
// ---------------------------------------------------------------------------
__global__ void embed_kernel(const int* __restrict__ x,
                             const float* __restrict__ emb,
                             bf16_t* __restrict__ X) {
    int m = blockIdx.x;            // 0..4095
    int t = m >> 7, b = m & 127;
    int tok = (t == 0) ? 1 : x[b * T_SEQ + t];
    const float* src = emb + (size_t)tok * EMB;
    bf16_t* dst = X + (size_t)m * EMB;
    int c = threadIdx.x * 4;
    float4 v = *(const float4*)(src + c);
    dst[c + 0] = (bf16_t)v.x;
    dst[c + 1] = (bf16_t)v.y;
    dst[c + 2] = (bf16_t)v.z;
    dst[c + 3] = (bf16_t)v.w;
}

// ---------------------------------------------------------------------------
#define GLOAD_LDS16(g, l)                                                    \
    __builtin_amdgcn_global_load_lds(                                        \
        (const __attribute__((address_space(1))) void*)(g),                  \
        (__attribute__((address_space(3))) void*)(l), 16, 0, 0)

// ---------------------------------------------------------------------------
// GEMM 256x256, BK=64, 8 waves, 4-phase interleave, counted vmcnt, LDS XOR
// swizzle, nontemporal C stores (verified R12). Used for Gi0 AND logits.
// Requires M%256==0, N%256==0, K%64==0, K>=128.
// ---------------------------------------------------------------------------
template <int BIAS>
__global__ __launch_bounds__(512, 1) void gemm256_bf16_kernel(
    const bf16_t* __restrict__ A, const bf16_t* __restrict__ B,
    const float* __restrict__ bias, float* __restrict__ C,
    int M, int N, int K) {
    __shared__ __align__(16) bf16_t lds[2 * 2 * 16384];   // 128 KB

    const int NT = K >> 6;
    const int nbm = gridDim.y, nbn = gridDim.x;
    const int nwg = nbm * nbn;
    int lin = blockIdx.y * nbn + blockIdx.x;
    {
        int q = nwg >> 3, r = nwg & 7, x = lin & 7, i = lin >> 3;
        lin = (x < r ? x * (q + 1) : r * (q + 1) + (x - r) * q) + i;
    }
    const int bm = (lin % nbm) * 256;
    const int bn = (lin / nbm) * 256;

    const int tid = threadIdx.x, lane = tid & 63;
    const int w = tid >> 6, wm = w >> 2, wn = w & 3;
    const int r16 = lane & 15, sl = lane >> 4, r7 = r16 & 7;

    const int srow  = tid >> 3;
    const int sslot = (tid & 7) ^ (srow & 7);
    const bf16_t* agS = A + (size_t)(bm + srow) * K + sslot * 8;
    const bf16_t* bgS = B + (size_t)(bn + srow) * K + sslot * 8;

    const int colk0 = ((0 + sl) ^ r7) * 8;
    const int colk1 = ((4 + sl) ^ r7) * 8;
    const int arow = (wm * 128 + r16) * 64;
    const int brow = (wn * 64 + r16) * 64;

    f32x4 acc[8][4] = {};
    bf16x8 af[4][2], bf[4][2];

#pragma unroll
    for (int l = 0; l < 4; ++l)
        GLOAD_LDS16(agS + (size_t)(l * 64) * K, lds + l * 4096 + tid * 8);
#pragma unroll
    for (int l = 0; l < 4; ++l)
        GLOAD_LDS16(bgS + (size_t)(l * 64) * K, lds + 16384 + l * 4096 + tid * 8);
#pragma unroll
    for (int l = 0; l < 4; ++l)
        GLOAD_LDS16(agS + (size_t)(l * 64) * K + 64,
                    lds + 32768 + l * 4096 + tid * 8);
#pragma unroll
    for (int l = 0; l < 4; ++l)
        GLOAD_LDS16(bgS + (size_t)(l * 64) * K + 64,
                    lds + 49152 + l * 4096 + tid * 8);
    asm volatile("s_waitcnt vmcnt(8)" ::: "memory");
    __builtin_amdgcn_sched_barrier(0);
    __builtin_amdgcn_s_barrier();

#pragma unroll 1
    for (int kt = 0; kt < NT; ++kt) {
        const int cur = kt & 1;
        const bf16_t* Ab = lds + cur * 32768;
        const bf16_t* Bb = Ab + 16384;
        bf16_t* Sb = lds + cur * 32768;
        const bool st = (kt + 2 < NT);
        const size_t kof = (size_t)(kt + 2) * 64;

        // phase 0
#pragma unroll
        for (int fr = 0; fr < 4; ++fr) {
            af[fr][0] = *(const bf16x8*)(Ab + arow + fr * 1024 + colk0);
            af[fr][1] = *(const bf16x8*)(Ab + arow + fr * 1024 + colk1);
        }
#pragma unroll
        for (int nf = 0; nf < 2; ++nf) {
            bf[nf][0] = *(const bf16x8*)(Bb + brow + nf * 1024 + colk0);
            bf[nf][1] = *(const bf16x8*)(Bb + brow + nf * 1024 + colk1);
        }
        __builtin_amdgcn_sched_barrier(0);
        __builtin_amdgcn_s_barrier();
        asm volatile("s_waitcnt lgkmcnt(0)" ::: "memory");
        __builtin_amdgcn_sched_barrier(0);
        __builtin_amdgcn_s_setprio(1);
#pragma unroll
        for (int fr = 0; fr < 4; ++fr)
#pragma unroll
            for (int nf = 0; nf < 2; ++nf) {
                acc[fr][nf] = MFMA(af[fr][0], bf[nf][0], acc[fr][nf]);
                acc[fr][nf] = MFMA(af[fr][1], bf[nf][1], acc[fr][nf]);
            }
        __builtin_amdgcn_s_setprio(0);
        __builtin_amdgcn_sched_barrier(0);
        __builtin_amdgcn_s_barrier();

        // phase 1
#pragma unroll
        for (int nf = 2; nf < 4; ++nf) {
            bf[nf][0] = *(const bf16x8*)(Bb + brow + nf * 1024 + colk0);
            bf[nf][1] = *(const bf16x8*)(Bb + brow + nf * 1024 + colk1);
        }
        __builtin_amdgcn_sched_barrier(0);
        if (st) {
            GLOAD_LDS16(agS + kof, Sb + tid * 8);
            GLOAD_LDS16(agS + (size_t)128 * K + kof, Sb + 8192 + tid * 8);
        }
        __builtin_amdgcn_s_barrier();
        asm volatile("s_waitcnt lgkmcnt(0)" ::: "memory");
        __builtin_amdgcn_sched_barrier(0);
        __builtin_amdgcn_s_setprio(1);
#pragma unroll
        for (int fr = 0; fr < 4; ++fr)
#pragma unroll
            for (int nf = 2; nf < 4; ++nf) {
                acc[fr][nf] = MFMA(af[fr][0], bf[nf][0], acc[fr][nf]);
                acc[fr][nf] = MFMA(af[fr][1], bf[nf][1], acc[fr][nf]);
            }
        __builtin_amdgcn_s_setprio(0);
        __builtin_amdgcn_sched_barrier(0);
        __builtin_amdgcn_s_barrier();

        // phase 2
#pragma unroll
        for (int fr = 0; fr < 4; ++fr) {
            af[fr][0] = *(const bf16x8*)(Ab + arow + (fr + 4) * 1024 + colk0);
            af[fr][1] = *(const bf16x8*)(Ab + arow + (fr + 4) * 1024 + colk1);
        }
        __builtin_amdgcn_sched_barrier(0);
        if (st) {
#pragma unroll
            for (int l = 0; l < 4; ++l)
                GLOAD_LDS16(bgS + (size_t)(l * 64) * K + kof,
                            Sb + 16384 + l * 4096 + tid * 8);
        }
        __builtin_amdgcn_s_barrier();
        asm volatile("s_waitcnt lgkmcnt(0)" ::: "memory");
        __builtin_amdgcn_sched_barrier(0);
        __builtin_amdgcn_s_setprio(1);
#pragma unroll
        for (int fr = 0; fr < 4; ++fr)
#pragma unroll
            for (int nf = 0; nf < 2; ++nf) {
                acc[fr + 4][nf] = MFMA(af[fr][0], bf[nf][0], acc[fr + 4][nf]);
                acc[fr + 4][nf] = MFMA(af[fr][1], bf[nf][1], acc[fr + 4][nf]);
            }
        __builtin_amdgcn_s_setprio(0);
        __builtin_amdgcn_sched_barrier(0);
        __builtin_amdgcn_s_barrier();

        // phase 3
        if (st) {
            GLOAD_LDS16(agS + (size_t)64 * K + kof, Sb + 4096 + tid * 8);
            GLOAD_LDS16(agS + (size_t)192 * K + kof, Sb + 12288 + tid * 8);
        }
        if (kt + 2 < NT) {
            asm volatile("s_waitcnt vmcnt(8)" ::: "memory");
        } else if (kt + 1 < NT) {
            asm volatile("s_waitcnt vmcnt(0)" ::: "memory");
        }
        __builtin_amdgcn_sched_barrier(0);
        __builtin_amdgcn_s_setprio(1);
#pragma unroll
        for (int fr = 0; fr < 4; ++fr)
#pragma unroll
            for (int nf = 2; nf < 4; ++nf) {
                acc[fr + 4][nf] = MFMA(af[fr][0], bf[nf][0], acc[fr + 4][nf]);
                acc[fr + 4][nf] = MFMA(af[fr][1], bf[nf][1], acc[fr + 4][nf]);
            }
        __builtin_amdgcn_s_setprio(0);
        __builtin_amdgcn_sched_barrier(0);
        __builtin_amdgcn_s_barrier();
    }

    // epilogue: nontemporal C stores (keep A/B panels cache-resident)
#pragma unroll
    for (int fr = 0; fr < 8; ++fr) {
        const int row0 = bm + wm * 128 + fr * 16 + sl * 4;
#pragma unroll
        for (int nf = 0; nf < 4; ++nf) {
            const int col = bn + wn * 64 + nf * 16 + r16;
            float bv = 0.f;
            if (BIAS) bv = bias[col];
#pragma unroll
            for (int r = 0; r < 4; ++r)
                __builtin_nontemporal_store(
                    acc[fr][nf][r] + bv, &C[(size_t)(row0 + r) * N + col]);
        }
    }
}

// ---------------------------------------------------------------------------
// Fused dataflow scan (R15, verified 907 µs): 3 roles x 64 blocks, per-wave
// early publish, wave-flag protocol wfl[role*256 + cb*4 + w].
// ---------------------------------------------------------------------------
__global__ __launch_bounds__(256, 1) void fused_scan_kernel(
    const bf16_t* __restrict__ h0ib, const bf16_t* __restrict__ h1ib,
    const float* __restrict__ enc_hid,
    const bf16_t* __restrict__ whh0, const bf16_t* __restrict__ wih1,
    const bf16_t* __restrict__ whh1,
    const float* __restrict__ bhh0, const float* __restrict__ bih1,
    const float* __restrict__ bhh1,
    float* __restrict__ Gi, bf16_t* __restrict__ H0b,
    bf16_t* __restrict__ H1b, unsigned* __restrict__ wfl) {
    __shared__ __align__(16) float Sg[4][3][128][16];   // 96 KB

    const int tid  = threadIdx.x;
    const int lane = tid & 63;
    const int w    = tid >> 6;          // k-slice owner
    const int role = blockIdx.x >> 6;   // 0=L0, 1=G, 2=L1
    const int cb   = blockIdx.x & 63;
    const int c0   = cb * 16;
    const int r16  = lane & 15;
    const int kq   = (lane >> 4) * 8;

    const int FL0 = 0, FG = 256, FL1 = 512;

    const bf16_t* whh = role == 0 ? whh0 : (role == 1 ? wih1 : whh1);
    const float*  bia = role == 0 ? bhh0 : (role == 1 ? bih1 : bhh1);

    bf16x8 wf[3][8];
#pragma unroll
    for (int g = 0; g < 3; ++g)
#pragma unroll
        for (int kf = 0; kf < 8; ++kf)
            wf[g][kf] = *(const bf16x8*)(
                whh + (size_t)(g * HID + c0 + r16) * HID + w * 256 + kf * 32 + kq);

    const int cg   = tid & 3;
    const int rloc = tid >> 2;
    const int ce   = c0 + cg * 4;

    float bh[3][4];
#pragma unroll
    for (int g = 0; g < 3; ++g)
#pragma unroll
        for (int j = 0; j < 4; ++j) bh[g][j] = bia[g * HID + ce + j];

    float hp[2][4];
    if (role != 1) {
        const float* h0f = enc_hid + (role == 2 ? BHID : 0);
#pragma unroll
        for (int i = 0; i < 2; ++i)
#pragma unroll
            for (int j = 0; j < 4; ++j)
                hp[i][j] = h0f[(size_t)(rloc + i * 64) * HID + ce + j];
    }

    // role 0: prefetch Gi0 for t = 0
    f32x4 gi[2][3];
    if (role == 0) {
#pragma unroll
        for (int i = 0; i < 2; ++i) {
            const size_t gb = (size_t)(rloc + i * 64) * G3 + ce;
            gi[i][0] = *(const f32x4*)(Gi + gb);
            gi[i][1] = *(const f32x4*)(Gi + gb + HID);
            gi[i][2] = *(const f32x4*)(Gi + gb + 2 * HID);
        }
    }

    for (int t = 0; t < T_SEQ; ++t) {
        // ---- wait on producers (wave-flag granularity) ----
        if (role == 0) {
            if (t && tid < 64) {
#pragma unroll
                for (int j = 0; j < 4; ++j)
                    while (flag_ld(&wfl[FL0 + tid * 4 + j]) < (unsigned)t)
                        __builtin_amdgcn_s_sleep(1);
            }
        } else if (role == 1) {
            if (tid < 64) {
#pragma unroll
                for (int j = 0; j < 4; ++j)
                    while (flag_ld(&wfl[FL0 + tid * 4 + j]) < (unsigned)(t + 1))
                        __builtin_amdgcn_s_sleep(1);
            }
        } else {
            if (tid < 64) {
                if (t) {
#pragma unroll
                    for (int j = 0; j < 4; ++j)
                        while (flag_ld(&wfl[FL1 + tid * 4 + j]) < (unsigned)t)
                            __builtin_amdgcn_s_sleep(1);
                }
            } else if (tid < 68) {
                while (flag_ld(&wfl[FG + cb * 4 + (tid - 64)]) <
                       (unsigned)(t + 1))
                    __builtin_amdgcn_s_sleep(1);
            }
        }
        __syncthreads();

        // ---- role 2: gi1 sc-read (G block cb confirmed done) ----
        if (role == 2) {
#pragma unroll
            for (int i = 0; i < 2; ++i) {
                const size_t gb =
                    ((size_t)t * BATCH + rloc + i * 64) * G3 + ce;
#pragma unroll
                for (int g = 0; g < 3; ++g) {
                    U128cast u;
                    const unsigned long long* p =
                        (const unsigned long long*)(Gi + gb + g * HID);
                    u.u[0] = __hip_atomic_load(p, __ATOMIC_RELAXED,
                                               __HIP_MEMORY_SCOPE_SYSTEM);
                    u.u[1] = __hip_atomic_load(p + 1, __ATOMIC_RELAXED,
                                               __HIP_MEMORY_SCOPE_SYSTEM);
                    gi[i][g] = u.v;
                }
            }
        }

        // ---- A source ----
        const bf16_t* hb =
            role == 0 ? (t ? H0b + (size_t)(t - 1) * BHID : h0ib)
          : role == 1 ? (H0b + (size_t)t * BHID)
                      : (t ? H1b + (size_t)(t - 1) * BHID : h1ib);

        // ---- MFMA phase: 4-deep pipelined af loads ----
        f32x4 acc[3][8] = {};
        bf16x8 af[4][8];
#define LD_GROUP(buf, kf)                                                    \
    {                                                                        \
        const int kbase = w * 256 + (kf) * 32 + kq;                          \
        _Pragma("unroll") for (int rf = 0; rf < 8; ++rf)                     \
            af[buf][rf] =                                                    \
                *(const bf16x8*)(hb + (size_t)(rf * 16 + r16) * HID + kbase); \
    }
        LD_GROUP(0, 0)
        LD_GROUP(1, 1)
        LD_GROUP(2, 2)
#pragma unroll
        for (int kf = 0; kf < 8; ++kf) {
            if (kf + 3 < 8) LD_GROUP((kf + 3) & 3, kf + 3)
#pragma unroll
            for (int rf = 0; rf < 8; ++rf) {
                acc[0][rf] = MFMA(af[kf & 3][rf], wf[0][kf], acc[0][rf]);
                acc[1][rf] = MFMA(af[kf & 3][rf], wf[1][kf], acc[1][rf]);
                acc[2][rf] = MFMA(af[kf & 3][rf], wf[2][kf], acc[2][rf]);
            }
        }
#undef LD_GROUP

#pragma unroll
        for (int g = 0; g < 3; ++g)
#pragma unroll
            for (int rf = 0; rf < 8; ++rf)
#pragma unroll
                for (int r = 0; r < 4; ++r)
                    Sg[w][g][rf * 16 + (lane >> 4) * 4 + r][r16] = acc[g][rf][r];
        __syncthreads();

        // ---- epilogue ----
#pragma unroll
        for (int i = 0; i < 2; ++i) {
            const int row = rloc + i * 64;
            f32x4 gr = *(const f32x4*)&Sg[0][0][row][cg * 4];
            f32x4 gz = *(const f32x4*)&Sg[0][1][row][cg * 4];
            f32x4 gn = *(const f32x4*)&Sg[0][2][row][cg * 4];
#pragma unroll
            for (int ks = 1; ks < 4; ++ks) {
                gr += *(const f32x4*)&Sg[ks][0][row][cg * 4];
                gz += *(const f32x4*)&Sg[ks][1][row][cg * 4];
                gn += *(const f32x4*)&Sg[ks][2][row][cg * 4];
            }
            if (role == 1) {
                const size_t gb = ((size_t)t * BATCH + row) * G3 + ce;
                U128cast s0, s1, s2;
#pragma unroll
                for (int j = 0; j < 4; ++j) {
                    s0.v[j] = gr[j] + bh[0][j];
                    s1.v[j] = gz[j] + bh[1][j];
                    s2.v[j] = gn[j] + bh[2][j];
                }
                unsigned long long* p0 = (unsigned long long*)(Gi + gb);
                unsigned long long* p1 = (unsigned long long*)(Gi + gb + HID);
                unsigned long long* p2 = (unsigned long long*)(Gi + gb + 2 * HID);
                __hip_atomic_store(p0, s0.u[0], __ATOMIC_RELAXED, __HIP_MEMORY_SCOPE_SYSTEM);
                __hip_atomic_store(p0 + 1, s0.u[1], __ATOMIC_RELAXED, __HIP_MEMORY_SCOPE_SYSTEM);
                __hip_atomic_store(p1, s1.u[0], __ATOMIC_RELAXED, __HIP_MEMORY_SCOPE_SYSTEM);
                __hip_atomic_store(p1 + 1, s1.u[1], __ATOMIC_RELAXED, __HIP_MEMORY_SCOPE_SYSTEM);
                __hip_atomic_store(p2, s2.u[0], __ATOMIC_RELAXED, __HIP_MEMORY_SCOPE_SYSTEM);
                __hip_atomic_store(p2 + 1, s2.u[1], __ATOMIC_RELAXED, __HIP_MEMORY_SCOPE_SYSTEM);
            } else {
                U64cast hb4;
#pragma unroll
                for (int j = 0; j < 4; ++j) {
                    float rr = 1.f / (1.f + __expf(-(gi[i][0][j] + gr[j] + bh[0][j])));
                    float zz = 1.f / (1.f + __expf(-(gi[i][1][j] + gz[j] + bh[1][j])));
                    float nn = tanhf(gi[i][2][j] + rr * (gn[j] + bh[2][j]));
                    float h  = (1.f - zz) * nn + zz * hp[i][j];
                    hp[i][j] = h;
                    hb4.v[j] = (bf16_t)h;
                }
                bf16_t* dst = (role == 0 ? H0b : H1b) +
                              (size_t)t * BHID + (size_t)row * HID + ce;
                __hip_atomic_store((unsigned long long*)dst, hb4.u,
                                   __ATOMIC_RELAXED, __HIP_MEMORY_SCOPE_SYSTEM);
            }
        }

        // ---- per-wave EARLY publish: own stores drained -> own flag ----
        asm volatile("s_waitcnt vmcnt(0)" ::: "memory");
        __builtin_amdgcn_sched_barrier(0);
        if (lane == 0)
            flag_st(&wfl[role * 256 + cb * 4 + w], (unsigned)(t + 1));

        // ---- role 0: prefetch Gi0(t+1), off the critical path ----
        if (role == 0 && t + 1 < T_SEQ) {
#pragma unroll
            for (int i = 0; i < 2; ++i) {
                const size_t gb =
                    ((size_t)(t + 1) * BATCH + rloc + i * 64) * G3 + ce;
                gi[i][0] = *(const f32x4*)(Gi + gb);
                gi[i][1] = *(const f32x4*)(Gi + gb + HID);
                gi[i][2] = *(const f32x4*)(Gi + gb + 2 * HID);
            }
        }
        __syncthreads();   // Sg protection for next iteration
    }
}

// ---------------------------------------------------------------------------
extern "C" void kernel_launch(void* const* d_in, const int* in_sizes, int n_in,
                              void* d_out, int out_size, void* d_ws, size_t ws_size,
                              hipStream_t stream) {
    const int*   x        = (const int*)d_in[0];
    const float* enc_hid  = (const float*)d_in[2];   // [2,128,1024]
    const float* emb      = (const float*)d_in[3];
    const float* w_ih0    = (const float*)d_in[4];
    const float* w_hh0    = (const float*)d_in[5];
    const float* b_ih0    = (const float*)d_in[6];
    const float* b_hh0    = (const float*)d_in[7];
    const float* w_ih1    = (const float*)d_in[8];
    const float* w_hh1    = (const float*)d_in[9];
    const float* b_ih1    = (const float*)d_in[10];
    const float* b_hh1    = (const float*)d_in[11];
    const float* w_dec    = (const float*)d_in[12];
    const float* b_dec    = (const float*)d_in[13];
    float* out = (float*)d_out;

    char* ws = (char*)d_ws;
    size_t off = 0;
    auto alloc = [&](size_t bytes) {
        void* p = ws + off;
        off += (bytes + 255) & ~(size_t)255;
        return p;
    };
    unsigned* wfl  = (unsigned*)alloc(4096);   // 768 wave-flags
    bf16_t* Xb     = (bf16_t*)alloc((size_t)MROWS * EMB * 2);
    bf16_t* Wih0b  = (bf16_t*)alloc((size_t)G3 * EMB * 2);
    bf16_t* Whh0b  = (bf16_t*)alloc((size_t)G3 * HID * 2);
    bf16_t* Wih1b  = (bf16_t*)alloc((size_t)G3 * HID * 2);
    bf16_t* Whh1b  = (bf16_t*)alloc((size_t)G3 * HID * 2);
    bf16_t* Wdecb  = (bf16_t*)alloc((size_t)VOC * HID * 2);
    bf16_t* h0ib   = (bf16_t*)alloc((size_t)BATCH * HID * 2);
    bf16_t* h1ib   = (bf16_t*)alloc((size_t)BATCH * HID * 2);
    float*  Gi     = (float*)alloc((size_t)MROWS * G3 * 4);
    bf16_t* H0b    = (bf16_t*)alloc((size_t)MROWS * HID * 2);
    bf16_t* H1b    = (bf16_t*)alloc((size_t)MROWS * HID * 2);

    hipMemsetAsync(wfl, 0, 4096, stream);

    // all f32->bf16 conversions in one launch
    fused_cvt_kernel<<<43008, 256, 0, stream>>>(
        w_ih0, w_hh0, w_ih1, w_hh1, w_dec, enc_hid,
        Wih0b, Whh0b, Wih1b, Whh1b, Wdecb, h0ib, h1ib);

    embed_kernel<<<MROWS, 128, 0, stream>>>(x, emb, Xb);

    // Gi0 = X @ w_ih0^T + b_ih0 -> [4096, 3072]  (256² 8-phase, K=512)
    gemm256_bf16_kernel<1><<<dim3(G3 / 256, MROWS / 256), 512, 0, stream>>>(
        Xb, Wih0b, b_ih0, Gi, MROWS, G3, EMB);

    // fused dataflow scan: L0 + Gi1 + L1 (per-wave early publish)
    fused_scan_kernel<<<192, 256, 0, stream>>>(
        h0ib, h1ib, enc_hid, Whh0b, Wih1b, Whh1b,
        b_hh0, b_ih1, b_hh1, Gi, H0b, H1b, wfl);

    // logits = H1 @ w_dec^T + b_dec -> [4096, 32000]  (nt C stores)
    gemm256_bf16_kernel<1><<<dim3(VOC / 256, MROWS / 256), 512, 0, stream>>>(
        H1b, Wdecb, b_dec, out, MROWS, VOC, HID);
}

// Round 18
// 878.595 us; speedup vs baseline: 1.2838x; 1.0584x over previous
//
#include <hip/hip_runtime.h>
#include <hip/hip_bf16.h>
#include <stdint.h>

#define T_SEQ 32
#define BATCH 128
#define EMB   512
#define HID   1024
#define VOC   32000
#define G3    (3 * HID)            // 3072
#define MROWS (T_SEQ * BATCH)      // 4096
#define BHID  (BATCH * HID)

typedef __bf16 bf16_t;
typedef __bf16 bf16x8 __attribute__((ext_vector_type(8)));
typedef __bf16 bf16x4 __attribute__((ext_vector_type(4)));
typedef float  f32x4  __attribute__((ext_vector_type(4)));

#define MFMA(a, b, c) __builtin_amdgcn_mfma_f32_16x16x32_bf16((a), (b), (c), 0, 0, 0)

union U64cast  { bf16x4 v; unsigned long long u; };
union U128cast { f32x4 v; unsigned long long u[2]; };

__device__ __forceinline__ unsigned flag_ld(const unsigned* p) {
    return __hip_atomic_load(p, __ATOMIC_RELAXED, __HIP_MEMORY_SCOPE_SYSTEM);
}
__device__ __forceinline__ void flag_st(unsigned* p, unsigned v) {
    __hip_atomic_store(p, v, __ATOMIC_RELAXED, __HIP_MEMORY_SCOPE_SYSTEM);
}

// ---------------------------------------------------------------------------
// Fused f32 -> bf16 conversion: small tensors only (w_dec is converted
// inside the scan kernel's spare blocks). Segments (1024 elems/block):
// w_ih0 1536 | w_hh0 3072 | w_ih1 3072 | w_hh1 3072 | h0 128 | h1 128.
// ---------------------------------------------------------------------------
__global__ void fused_cvt_kernel(
    const float* __restrict__ w_ih0, const float* __restrict__ w_hh0,
    const float* __restrict__ w_ih1, const float* __restrict__ w_hh1,
    const float* __restrict__ enc_hid,
    bf16_t* __restrict__ Wih0b, bf16_t* __restrict__ Whh0b,
    bf16_t* __restrict__ Wih1b, bf16_t* __restrict__ Whh1b,
    bf16_t* __restrict__ h0ib, bf16_t* __restrict__ h1ib) {
    const int b = blockIdx.x;
    const float* src;
    bf16_t* dst;
    int base;
    if (b < 1536)       { src = w_ih0;          dst = Wih0b; base = b; }
    else if (b < 4608)  { src = w_hh0;          dst = Whh0b; base = b - 1536; }
    else if (b < 7680)  { src = w_ih1;          dst = Wih1b; base = b - 4608; }
    else if (b < 10752) { src = w_hh1;          dst = Whh1b; base = b - 7680; }
    else if (b < 10880) { src = enc_hid;        dst = h0ib;  base = b - 10752; }
    else                { src = enc_hid + BHID; dst = h1ib;  base = b - 10880; }
    const int i = base * 1024 + threadIdx.x * 4;
    float4 v = *(const float4*)(src + i);
    dst[i + 0] = (bf16_t)v.x;
    dst[i + 1] = (bf16_t)v.y;
    dst[i + 2] = (bf16_t)v.z;
    dst[i + 3] = (bf16_t)v.w;
}

// ---------------------------------------------------------------------------
// Embedding gather
// ---------------------------------------------------------------------------
__global__ void embed_kernel(const int* __restrict__ x,
                             const float* __restrict__ emb,
                             bf16_t* __restrict__ X) {
    int m = blockIdx.x;            // 0..4095
    int t = m >> 7, b = m & 127;
    int tok = (t == 0) ? 1 : x[b * T_SEQ + t];
    const float* src = emb + (size_t)tok * EMB;
    bf16_t* dst = X + (size_t)m * EMB;
    int c = threadIdx.x * 4;
    float4 v = *(const float4*)(src + c);
    dst[c + 0] = (bf16_t)v.x;
    dst[c + 1] = (bf16_t)v.y;
    dst[c + 2] = (bf16_t)v.z;
    dst[c + 3] = (bf16_t)v.w;
}

// ---------------------------------------------------------------------------
#define GLOAD_LDS16(g, l)                                                    \
    __builtin_amdgcn_global_load_lds(                                        \
        (const __attribute__((address_space(1))) void*)(g),                  \
        (__attribute__((address_space(3))) void*)(l), 16, 0, 0)

// ---------------------------------------------------------------------------
// GEMM 128x128 (m97 structure) — Gi0 GEMM (R15-proven; 256² port regressed
// at this shape in R17: 192 blocks/NT=8 is too shallow to amortize).
// ---------------------------------------------------------------------------
template <int BIAS>
__global__ __launch_bounds__(256) void gemm_bf16_kernel(
    const bf16_t* __restrict__ A, const bf16_t* __restrict__ B,
    const float* __restrict__ bias, float* __restrict__ C,
    int M, int N, int K) {
    __shared__ __align__(16) bf16_t As[128 * 32];
    __shared__ __align__(16) bf16_t Bs[128 * 32];

    const int nbm = gridDim.y, nbn = gridDim.x;
    const int nwg = nbm * nbn;
    int lin = blockIdx.y * nbn + blockIdx.x;
    if ((nwg & 7) == 0) {
        int xcd = lin & 7, idx = lin >> 3;
        lin = xcd * (nwg >> 3) + idx;
    }
    const int bm = (lin % nbm) * 128;
    const int bn = (lin / nbm) * 128;

    const int tid  = threadIdx.x;
    const int lane = tid & 63;
    const int w    = tid >> 6;
    const int wr   = w >> 1, wc = w & 1;

    f32x4 acc[4][4] = {};

    const int lrow = tid >> 2;
    const int lcol = (tid & 3) * 8;
    const bf16_t* ag = A + (size_t)(bm + lrow) * K + lcol;
    const bf16_t* bg = B + (size_t)(bn + lrow) * K + lcol;
    bf16_t* asl0 = As + lrow * 32 + lcol;
    bf16_t* asl1 = As + (lrow + 64) * 32 + lcol;
    bf16_t* bsl0 = Bs + lrow * 32 + lcol;
    bf16_t* bsl1 = Bs + (lrow + 64) * 32 + lcol;

    const int r16 = lane & 15;
    const int kh  = (lane >> 4) * 8;

    for (int k0 = 0; k0 < K; k0 += 32) {
        GLOAD_LDS16(ag + k0, asl0);
        GLOAD_LDS16(ag + (size_t)64 * K + k0, asl1);
        GLOAD_LDS16(bg + k0, bsl0);
        GLOAD_LDS16(bg + (size_t)64 * K + k0, bsl1);
        __syncthreads();

        bf16x8 af[4], bf[4];
#pragma unroll
        for (int mi = 0; mi < 4; ++mi)
            af[mi] = *(const bf16x8*)(As + (wr * 64 + mi * 16 + r16) * 32 + kh);
#pragma unroll
        for (int ni = 0; ni < 4; ++ni)
            bf[ni] = *(const bf16x8*)(Bs + (wc * 64 + ni * 16 + r16) * 32 + kh);
#pragma unroll
        for (int mi = 0; mi < 4; ++mi)
#pragma unroll
            for (int ni = 0; ni < 4; ++ni)
                acc[mi][ni] = MFMA(af[mi], bf[ni], acc[mi][ni]);
        __syncthreads();
    }

#pragma unroll
    for (int mi = 0; mi < 4; ++mi) {
        const int row0 = bm + wr * 64 + mi * 16 + (lane >> 4) * 4;
#pragma unroll
        for (int ni = 0; ni < 4; ++ni) {
            const int col = bn + wc * 64 + ni * 16 + r16;
            float bv = 0.f;
            if (BIAS) bv = bias[col];
#pragma unroll
            for (int r = 0; r < 4; ++r)
                C[(size_t)(row0 + r) * N + col] = acc[mi][ni][r] + bv;
        }
    }
}

// ---------------------------------------------------------------------------
// GEMM 256x256, BK=64, 8 waves, 4-phase interleave, counted vmcnt, LDS XOR
// swizzle, nontemporal C stores (verified R12) — logits GEMM only.
// ---------------------------------------------------------------------------
template <int BIAS>
__global__ __launch_bounds__(512, 1) void gemm256_bf16_kernel(
    const bf16_t* __restrict__ A, const bf16_t* __restrict__ B,
    const float* __restrict__ bias, float* __restrict__ C,
    int M, int N, int K) {
    __shared__ __align__(16) bf16_t lds[2 * 2 * 16384];   // 128 KB

    const int NT = K >> 6;
    const int nbm = gridDim.y, nbn = gridDim.x;
    const int nwg = nbm * nbn;
    int lin = blockIdx.y * nbn + blockIdx.x;
    {
        int q = nwg >> 3, r = nwg & 7, x = lin & 7, i = lin >> 3;
        lin = (x < r ? x * (q + 1) : r * (q + 1) + (x - r) * q) + i;
    }
    const int bm = (lin % nbm) * 256;
    const int bn = (lin / nbm) * 256;

    const int tid = threadIdx.x, lane = tid & 63;
    const int w = tid >> 6, wm = w >> 2, wn = w & 3;
    const int r16 = lane & 15, sl = lane >> 4, r7 = r16 & 7;

    const int srow  = tid >> 3;
    const int sslot = (tid & 7) ^ (srow & 7);
    const bf16_t* agS = A + (size_t)(bm + srow) * K + sslot * 8;
    const bf16_t* bgS = B + (size_t)(bn + srow) * K + sslot * 8;

    const int colk0 = ((0 + sl) ^ r7) * 8;
    const int colk1 = ((4 + sl) ^ r7) * 8;
    const int arow = (wm * 128 + r16) * 64;
    const int brow = (wn * 64 + r16) * 64;

    f32x4 acc[8][4] = {};
    bf16x8 af[4][2], bf[4][2];

#pragma unroll
    for (int l = 0; l < 4; ++l)
        GLOAD_LDS16(agS + (size_t)(l * 64) * K, lds + l * 4096 + tid * 8);
#pragma unroll
    for (int l = 0; l < 4; ++l)
        GLOAD_LDS16(bgS + (size_t)(l * 64) * K, lds + 16384 + l * 4096 + tid * 8);
#pragma unroll
    for (int l = 0; l < 4; ++l)
        GLOAD_LDS16(agS + (size_t)(l * 64) * K + 64,
                    lds + 32768 + l * 4096 + tid * 8);
#pragma unroll
    for (int l = 0; l < 4; ++l)
        GLOAD_LDS16(bgS + (size_t)(l * 64) * K + 64,
                    lds + 49152 + l * 4096 + tid * 8);
    asm volatile("s_waitcnt vmcnt(8)" ::: "memory");
    __builtin_amdgcn_sched_barrier(0);
    __builtin_amdgcn_s_barrier();

#pragma unroll 1
    for (int kt = 0; kt < NT; ++kt) {
        const int cur = kt & 1;
        const bf16_t* Ab = lds + cur * 32768;
        const bf16_t* Bb = Ab + 16384;
        bf16_t* Sb = lds + cur * 32768;
        const bool st = (kt + 2 < NT);
        const size_t kof = (size_t)(kt + 2) * 64;

        // phase 0
#pragma unroll
        for (int fr = 0; fr < 4; ++fr) {
            af[fr][0] = *(const bf16x8*)(Ab + arow + fr * 1024 + colk0);
            af[fr][1] = *(const bf16x8*)(Ab + arow + fr * 1024 + colk1);
        }
#pragma unroll
        for (int nf = 0; nf < 2; ++nf) {
            bf[nf][0] = *(const bf16x8*)(Bb + brow + nf * 1024 + colk0);
            bf[nf][1] = *(const bf16x8*)(Bb + brow + nf * 1024 + colk1);
        }
        __builtin_amdgcn_sched_barrier(0);
        __builtin_amdgcn_s_barrier();
        asm volatile("s_waitcnt lgkmcnt(0)" ::: "memory");
        __builtin_amdgcn_sched_barrier(0);
        __builtin_amdgcn_s_setprio(1);
#pragma unroll
        for (int fr = 0; fr < 4; ++fr)
#pragma unroll
            for (int nf = 0; nf < 2; ++nf) {
                acc[fr][nf] = MFMA(af[fr][0], bf[nf][0], acc[fr][nf]);
                acc[fr][nf] = MFMA(af[fr][1], bf[nf][1], acc[fr][nf]);
            }
        __builtin_amdgcn_s_setprio(0);
        __builtin_amdgcn_sched_barrier(0);
        __builtin_amdgcn_s_barrier();

        // phase 1
#pragma unroll
        for (int nf = 2; nf < 4; ++nf) {
            bf[nf][0] = *(const bf16x8*)(Bb + brow + nf * 1024 + colk0);
            bf[nf][1] = *(const bf16x8*)(Bb + brow + nf * 1024 + colk1);
        }
        __builtin_amdgcn_sched_barrier(0);
        if (st) {
            GLOAD_LDS16(agS + kof, Sb + tid * 8);
            GLOAD_LDS16(agS + (size_t)128 * K + kof, Sb + 8192 + tid * 8);
        }
        __builtin_amdgcn_s_barrier();
        asm volatile("s_waitcnt lgkmcnt(0)" ::: "memory");
        __builtin_amdgcn_sched_barrier(0);
        __builtin_amdgcn_s_setprio(1);
#pragma unroll
        for (int fr = 0; fr < 4; ++fr)
#pragma unroll
            for (int nf = 2; nf < 4; ++nf) {
                acc[fr][nf] = MFMA(af[fr][0], bf[nf][0], acc[fr][nf]);
                acc[fr][nf] = MFMA(af[fr][1], bf[nf][1], acc[fr][nf]);
            }
        __builtin_amdgcn_s_setprio(0);
        __builtin_amdgcn_sched_barrier(0);
        __builtin_amdgcn_s_barrier();

        // phase 2
#pragma unroll
        for (int fr = 0; fr < 4; ++fr) {
            af[fr][0] = *(const bf16x8*)(Ab + arow + (fr + 4) * 1024 + colk0);
            af[fr][1] = *(const bf16x8*)(Ab + arow + (fr + 4) * 1024 + colk1);
        }
        __builtin_amdgcn_sched_barrier(0);
        if (st) {
#pragma unroll
            for (int l = 0; l < 4; ++l)
                GLOAD_LDS16(bgS + (size_t)(l * 64) * K + kof,
                            Sb + 16384 + l * 4096 + tid * 8);
        }
        __builtin_amdgcn_s_barrier();
        asm volatile("s_waitcnt lgkmcnt(0)" ::: "memory");
        __builtin_amdgcn_sched_barrier(0);
        __builtin_amdgcn_s_setprio(1);
#pragma unroll
        for (int fr = 0; fr < 4; ++fr)
#pragma unroll
            for (int nf = 0; nf < 2; ++nf) {
                acc[fr + 4][nf] = MFMA(af[fr][0], bf[nf][0], acc[fr + 4][nf]);
                acc[fr + 4][nf] = MFMA(af[fr][1], bf[nf][1], acc[fr + 4][nf]);
            }
        __builtin_amdgcn_s_setprio(0);
        __builtin_amdgcn_sched_barrier(0);
        __builtin_amdgcn_s_barrier();

        // phase 3
        if (st) {
            GLOAD_LDS16(agS + (size_t)64 * K + kof, Sb + 4096 + tid * 8);
            GLOAD_LDS16(agS + (size_t)192 * K + kof, Sb + 12288 + tid * 8);
        }
        if (kt + 2 < NT) {
            asm volatile("s_waitcnt vmcnt(8)" ::: "memory");
        } else if (kt + 1 < NT) {
            asm volatile("s_waitcnt vmcnt(0)" ::: "memory");
        }
        __builtin_amdgcn_sched_barrier(0);
        __builtin_amdgcn_s_setprio(1);
#pragma unroll
        for (int fr = 0; fr < 4; ++fr)
#pragma unroll
            for (int nf = 2; nf < 4; ++nf) {
                acc[fr + 4][nf] = MFMA(af[fr][0], bf[nf][0], acc[fr + 4][nf]);
                acc[fr + 4][nf] = MFMA(af[fr][1], bf[nf][1], acc[fr + 4][nf]);
            }
        __builtin_amdgcn_s_setprio(0);
        __builtin_amdgcn_sched_barrier(0);
        __builtin_amdgcn_s_barrier();
    }

    // epilogue: nontemporal C stores (keep A/B panels cache-resident)
#pragma unroll
    for (int fr = 0; fr < 8; ++fr) {
        const int row0 = bm + wm * 128 + fr * 16 + sl * 4;
#pragma unroll
        for (int nf = 0; nf < 4; ++nf) {
            const int col = bn + wn * 64 + nf * 16 + r16;
            float bv = 0.f;
            if (BIAS) bv = bias[col];
#pragma unroll
            for (int r = 0; r < 4; ++r)
                __builtin_nontemporal_store(
                    acc[fr][nf][r] + bv, &C[(size_t)(row0 + r) * N + col]);
        }
    }
}

// ---------------------------------------------------------------------------
// Fused dataflow scan (R15, verified 907 µs) + R18: 64 spare blocks
// (bid 192-255) convert w_dec f32->bf16 while the scan runs.
//  role 0 (bid 0-63):   L0
//  role 1 (bid 64-127): G (gi1 -> Gi slot t)
//  role 2 (bid 128-191): L1
//  bid 192-255: w_dec cvt (grid-stride streaming copy, no flags)
// 96 KB LDS -> 1 block/CU -> all 256 blocks co-resident; cvt blocks are
// dependency-free so the scan's DAG is unchanged.
// ---------------------------------------------------------------------------
__global__ __launch_bounds__(256, 1) void fused_scan_kernel(
    const bf16_t* __restrict__ h0ib, const bf16_t* __restrict__ h1ib,
    const float* __restrict__ enc_hid,
    const bf16_t* __restrict__ whh0, const bf16_t* __restrict__ wih1,
    const bf16_t* __restrict__ whh1,
    const float* __restrict__ bhh0, const float* __restrict__ bih1,
    const float* __restrict__ bhh1,
    float* __restrict__ Gi, bf16_t* __restrict__ H0b,
    bf16_t* __restrict__ H1b, unsigned* __restrict__ wfl,
    const float* __restrict__ wdec_f, bf16_t* __restrict__ Wdecb) {
    __shared__ __align__(16) float Sg[4][3][128][16];   // 96 KB

    const int tid  = threadIdx.x;
    const int bid  = blockIdx.x;

    if (bid >= 192) {
        // ---- w_dec f32 -> bf16 (32.768M elems; 64 blocks x 256 thr x 4) ----
        const int cvtid = (bid - 192) * 256 + tid;   // 0..16383
#pragma unroll 4
        for (int it = 0; it < 500; ++it) {
            const size_t i = ((size_t)it * 16384 + cvtid) * 4;
            float4 v = *(const float4*)(wdec_f + i);
            bf16_t* d = Wdecb + i;
            d[0] = (bf16_t)v.x;
            d[1] = (bf16_t)v.y;
            d[2] = (bf16_t)v.z;
            d[3] = (bf16_t)v.w;
        }
        return;
    }

    const int lane = tid & 63;
    const int w    = tid >> 6;          // k-slice owner
    const int role = bid >> 6;          // 0=L0, 1=G, 2=L1
    const int cb   = bid & 63;
    const int c0   = cb * 16;
    const int r16  = lane & 15;
    const int kq   = (lane >> 4) * 8;

    const int FL0 = 0, FG = 256, FL1 = 512;

    const bf16_t* whh = role == 0 ? whh0 : (role == 1 ? wih1 : whh1);
    const float*  bia = role == 0 ? bhh0 : (role == 1 ? bih1 : bhh1);

    bf16x8 wf[3][8];
#pragma unroll
    for (int g = 0; g < 3; ++g)
#pragma unroll
        for (int kf = 0; kf < 8; ++kf)
            wf[g][kf] = *(const bf16x8*)(
                whh + (size_t)(g * HID + c0 + r16) * HID + w * 256 + kf * 32 + kq);

    const int cg   = tid & 3;
    const int rloc = tid >> 2;
    const int ce   = c0 + cg * 4;

    float bh[3][4];
#pragma unroll
    for (int g = 0; g < 3; ++g)
#pragma unroll
        for (int j = 0; j < 4; ++j) bh[g][j] = bia[g * HID + ce + j];

    float hp[2][4];
    if (role != 1) {
        const float* h0f = enc_hid + (role == 2 ? BHID : 0);
#pragma unroll
        for (int i = 0; i < 2; ++i)
#pragma unroll
            for (int j = 0; j < 4; ++j)
                hp[i][j] = h0f[(size_t)(rloc + i * 64) * HID + ce + j];
    }

    // role 0: prefetch Gi0 for t = 0
    f32x4 gi[2][3];
    if (role == 0) {
#pragma unroll
        for (int i = 0; i < 2; ++i) {
            const size_t gb = (size_t)(rloc + i * 64) * G3 + ce;
            gi[i][0] = *(const f32x4*)(Gi + gb);
            gi[i][1] = *(const f32x4*)(Gi + gb + HID);
            gi[i][2] = *(const f32x4*)(Gi + gb + 2 * HID);
        }
    }

    for (int t = 0; t < T_SEQ; ++t) {
        // ---- wait on producers (wave-flag granularity) ----
        if (role == 0) {
            if (t && tid < 64) {
#pragma unroll
                for (int j = 0; j < 4; ++j)
                    while (flag_ld(&wfl[FL0 + tid * 4 + j]) < (unsigned)t)
                        __builtin_amdgcn_s_sleep(1);
            }
        } else if (role == 1) {
            if (tid < 64) {
#pragma unroll
                for (int j = 0; j < 4; ++j)
                    while (flag_ld(&wfl[FL0 + tid * 4 + j]) < (unsigned)(t + 1))
                        __builtin_amdgcn_s_sleep(1);
            }
        } else {
            if (tid < 64) {
                if (t) {
#pragma unroll
                    for (int j = 0; j < 4; ++j)
                        while (flag_ld(&wfl[FL1 + tid * 4 + j]) < (unsigned)t)
                            __builtin_amdgcn_s_sleep(1);
                }
            } else if (tid < 68) {
                while (flag_ld(&wfl[FG + cb * 4 + (tid - 64)]) <
                       (unsigned)(t + 1))
                    __builtin_amdgcn_s_sleep(1);
            }
        }
        __syncthreads();

        // ---- role 2: gi1 sc-read (G block cb confirmed done) ----
        if (role == 2) {
#pragma unroll
            for (int i = 0; i < 2; ++i) {
                const size_t gb =
                    ((size_t)t * BATCH + rloc + i * 64) * G3 + ce;
#pragma unroll
                for (int g = 0; g < 3; ++g) {
                    U128cast u;
                    const unsigned long long* p =
                        (const unsigned long long*)(Gi + gb + g * HID);
                    u.u[0] = __hip_atomic_load(p, __ATOMIC_RELAXED,
                                               __HIP_MEMORY_SCOPE_SYSTEM);
                    u.u[1] = __hip_atomic_load(p + 1, __ATOMIC_RELAXED,
                                               __HIP_MEMORY_SCOPE_SYSTEM);
                    gi[i][g] = u.v;
                }
            }
        }

        // ---- A source ----
        const bf16_t* hb =
            role == 0 ? (t ? H0b + (size_t)(t - 1) * BHID : h0ib)
          : role == 1 ? (H0b + (size_t)t * BHID)
                      : (t ? H1b + (size_t)(t - 1) * BHID : h1ib);

        // ---- MFMA phase: 4-deep pipelined af loads ----
        f32x4 acc[3][8] = {};
        bf16x8 af[4][8];
#define LD_GROUP(buf, kf)                                                    \
    {                                                                        \
        const int kbase = w * 256 + (kf) * 32 + kq;                          \
        _Pragma("unroll") for (int rf = 0; rf < 8; ++rf)                     \
            af[buf][rf] =                                                    \
                *(const bf16x8*)(hb + (size_t)(rf * 16 + r16) * HID + kbase); \
    }
        LD_GROUP(0, 0)
        LD_GROUP(1, 1)
        LD_GROUP(2, 2)
#pragma unroll
        for (int kf = 0; kf < 8; ++kf) {
            if (kf + 3 < 8) LD_GROUP((kf + 3) & 3, kf + 3)
#pragma unroll
            for (int rf = 0; rf < 8; ++rf) {
                acc[0][rf] = MFMA(af[kf & 3][rf], wf[0][kf], acc[0][rf]);
                acc[1][rf] = MFMA(af[kf & 3][rf], wf[1][kf], acc[1][rf]);
                acc[2][rf] = MFMA(af[kf & 3][rf], wf[2][kf], acc[2][rf]);
            }
        }
#undef LD_GROUP

#pragma unroll
        for (int g = 0; g < 3; ++g)
#pragma unroll
            for (int rf = 0; rf < 8; ++rf)
#pragma unroll
                for (int r = 0; r < 4; ++r)
                    Sg[w][g][rf * 16 + (lane >> 4) * 4 + r][r16] = acc[g][rf][r];
        __syncthreads();

        // ---- epilogue ----
#pragma unroll
        for (int i = 0; i < 2; ++i) {
            const int row = rloc + i * 64;
            f32x4 gr = *(const f32x4*)&Sg[0][0][row][cg * 4];
            f32x4 gz = *(const f32x4*)&Sg[0][1][row][cg * 4];
            f32x4 gn = *(const f32x4*)&Sg[0][2][row][cg * 4];
#pragma unroll
            for (int ks = 1; ks < 4; ++ks) {
                gr += *(const f32x4*)&Sg[ks][0][row][cg * 4];
                gz += *(const f32x4*)&Sg[ks][1][row][cg * 4];
                gn += *(const f32x4*)&Sg[ks][2][row][cg * 4];
            }
            if (role == 1) {
                const size_t gb = ((size_t)t * BATCH + row) * G3 + ce;
                U128cast s0, s1, s2;
#pragma unroll
                for (int j = 0; j < 4; ++j) {
                    s0.v[j] = gr[j] + bh[0][j];
                    s1.v[j] = gz[j] + bh[1][j];
                    s2.v[j] = gn[j] + bh[2][j];
                }
                unsigned long long* p0 = (unsigned long long*)(Gi + gb);
                unsigned long long* p1 = (unsigned long long*)(Gi + gb + HID);
                unsigned long long* p2 = (unsigned long long*)(Gi + gb + 2 * HID);
                __hip_atomic_store(p0, s0.u[0], __ATOMIC_RELAXED, __HIP_MEMORY_SCOPE_SYSTEM);
                __hip_atomic_store(p0 + 1, s0.u[1], __ATOMIC_RELAXED, __HIP_MEMORY_SCOPE_SYSTEM);
                __hip_atomic_store(p1, s1.u[0], __ATOMIC_RELAXED, __HIP_MEMORY_SCOPE_SYSTEM);
                __hip_atomic_store(p1 + 1, s1.u[1], __ATOMIC_RELAXED, __HIP_MEMORY_SCOPE_SYSTEM);
                __hip_atomic_store(p2, s2.u[0], __ATOMIC_RELAXED, __HIP_MEMORY_SCOPE_SYSTEM);
                __hip_atomic_store(p2 + 1, s2.u[1], __ATOMIC_RELAXED, __HIP_MEMORY_SCOPE_SYSTEM);
            } else {
                U64cast hb4;
#pragma unroll
                for (int j = 0; j < 4; ++j) {
                    float rr = 1.f / (1.f + __expf(-(gi[i][0][j] + gr[j] + bh[0][j])));
                    float zz = 1.f / (1.f + __expf(-(gi[i][1][j] + gz[j] + bh[1][j])));
                    float nn = tanhf(gi[i][2][j] + rr * (gn[j] + bh[2][j]));
                    float h  = (1.f - zz) * nn + zz * hp[i][j];
                    hp[i][j] = h;
                    hb4.v[j] = (bf16_t)h;
                }
                bf16_t* dst = (role == 0 ? H0b : H1b) +
                              (size_t)t * BHID + (size_t)row * HID + ce;
                __hip_atomic_store((unsigned long long*)dst, hb4.u,
                                   __ATOMIC_RELAXED, __HIP_MEMORY_SCOPE_SYSTEM);
            }
        }

        // ---- per-wave EARLY publish: own stores drained -> own flag ----
        asm volatile("s_waitcnt vmcnt(0)" ::: "memory");
        __builtin_amdgcn_sched_barrier(0);
        if (lane == 0)
            flag_st(&wfl[role * 256 + cb * 4 + w], (unsigned)(t + 1));

        // ---- role 0: prefetch Gi0(t+1), off the critical path ----
        if (role == 0 && t + 1 < T_SEQ) {
#pragma unroll
            for (int i = 0; i < 2; ++i) {
                const size_t gb =
                    ((size_t)(t + 1) * BATCH + rloc + i * 64) * G3 + ce;
                gi[i][0] = *(const f32x4*)(Gi + gb);
                gi[i][1] = *(const f32x4*)(Gi + gb + HID);
                gi[i][2] = *(const f32x4*)(Gi + gb + 2 * HID);
            }
        }
        __syncthreads();   // Sg protection for next iteration
    }
}

// ---------------------------------------------------------------------------
extern "C" void kernel_launch(void* const* d_in, const int* in_sizes, int n_in,
                              void* d_out, int out_size, void* d_ws, size_t ws_size,
                              hipStream_t stream) {
    const int*   x        = (const int*)d_in[0];
    const float* enc_hid  = (const float*)d_in[2];   // [2,128,1024]
    const float* emb      = (const float*)d_in[3];
    const float* w_ih0    = (const float*)d_in[4];
    const float* w_hh0    = (const float*)d_in[5];
    const float* b_ih0    = (const float*)d_in[6];
    const float* b_hh0    = (const float*)d_in[7];
    const float* w_ih1    = (const float*)d_in[8];
    const float* w_hh1    = (const float*)d_in[9];
    const float* b_ih1    = (const float*)d_in[10];
    const float* b_hh1    = (const float*)d_in[11];
    const float* w_dec    = (const float*)d_in[12];
    const float* b_dec    = (const float*)d_in[13];
    float* out = (float*)d_out;

    char* ws = (char*)d_ws;
    size_t off = 0;
    auto alloc = [&](size_t bytes) {
        void* p = ws + off;
        off += (bytes + 255) & ~(size_t)255;
        return p;
    };
    unsigned* wfl  = (unsigned*)alloc(4096);   // 768 wave-flags
    bf16_t* Xb     = (bf16_t*)alloc((size_t)MROWS * EMB * 2);
    bf16_t* Wih0b  = (bf16_t*)alloc((size_t)G3 * EMB * 2);
    bf16_t* Whh0b  = (bf16_t*)alloc((size_t)G3 * HID * 2);
    bf16_t* Wih1b  = (bf16_t*)alloc((size_t)G3 * HID * 2);
    bf16_t* Whh1b  = (bf16_t*)alloc((size_t)G3 * HID * 2);
    bf16_t* Wdecb  = (bf16_t*)alloc((size_t)VOC * HID * 2);
    bf16_t* h0ib   = (bf16_t*)alloc((size_t)BATCH * HID * 2);
    bf16_t* h1ib   = (bf16_t*)alloc((size_t)BATCH * HID * 2);
    float*  Gi     = (float*)alloc((size_t)MROWS * G3 * 4);
    bf16_t* H0b    = (bf16_t*)alloc((size_t)MROWS * HID * 2);
    bf16_t* H1b    = (bf16_t*)alloc((size_t)MROWS * HID * 2);

    hipMemsetAsync(wfl, 0, 4096, stream);

    // small f32->bf16 conversions (w_dec handled inside the scan kernel)
    fused_cvt_kernel<<<11008, 256, 0, stream>>>(
        w_ih0, w_hh0, w_ih1, w_hh1, enc_hid,
        Wih0b, Whh0b, Wih1b, Whh1b, h0ib, h1ib);

    embed_kernel<<<MROWS, 128, 0, stream>>>(x, emb, Xb);

    // Gi0 = X @ w_ih0^T + b_ih0 -> [4096, 3072]  (128² m97, R15-proven)
    gemm_bf16_kernel<1><<<dim3(G3 / 128, MROWS / 128), 256, 0, stream>>>(
        Xb, Wih0b, b_ih0, Gi, MROWS, G3, EMB);

    // fused dataflow scan (L0 + G + L1) ∥ w_dec conversion on spare CUs
    fused_scan_kernel<<<256, 256, 0, stream>>>(
        h0ib, h1ib, enc_hid, Whh0b, Wih1b, Whh1b,
        b_hh0, b_ih1, b_hh1, Gi, H0b, H1b, wfl, w_dec, Wdecb);

    // logits = H1 @ w_dec^T + b_dec -> [4096, 32000]  (nt C stores)
    gemm256_bf16_kernel<1><<<dim3(VOC / 256, MROWS / 256), 512, 0, stream>>>(
        H1b, Wdecb, b_dec, out, MROWS, VOC, HID);
}